// Round 9
// baseline (1004.754 us; speedup 1.0000x reference)
//
#include <hip/hip_runtime.h>
#include <hip/hip_bf16.h>

#define BSZ 128
#define NSQ 1024
#define NSTEPC 8
#define IND 768
#define HIDD 512
#define G4D 2048
#define MLPD 512
#define KXD 1280
#define NEGV -100000.0f
#define KSG 16   // K-split chunks for gates gemm (1280/16 = 80 = 5 tiles)

typedef __attribute__((ext_vector_type(4))) float f32x4;
typedef __attribute__((ext_vector_type(8))) short short8v;

__device__ __forceinline__ void gl16(const unsigned short* g, unsigned short* l) {
  __builtin_amdgcn_global_load_lds(
      (const __attribute__((address_space(1))) unsigned int*)(g),
      (__attribute__((address_space(3))) unsigned int*)(l), 16, 0, 0);
}

__device__ __forceinline__ void split2(float4 f0, float4 f1, short8v& hi, short8v& lo) {
  float fv[8] = {f0.x, f0.y, f0.z, f0.w, f1.x, f1.y, f1.z, f1.w};
#pragma unroll
  for (int j = 0; j < 8; ++j) {
    const unsigned ub = __builtin_bit_cast(unsigned, fv[j]);
    const unsigned hb = ub & 0xFFFF0000u;
    const float lf = fv[j] - __builtin_bit_cast(float, hb);
    hi[j] = (short)(hb >> 16);
    lo[j] = (short)(__builtin_bit_cast(unsigned, lf) >> 16);
  }
}

// tanh(x) = 1 - 2/(e^{2x}+1)
__device__ __forceinline__ float tanh_fast(float x) {
  x = fminf(fmaxf(x, -15.0f), 15.0f);
  float e = __builtin_amdgcn_exp2f(x * 2.8853900817779268f);
  float r = __builtin_amdgcn_rcpf(e + 1.0f);
  return fmaf(-2.0f, r, 1.0f);
}

// ---------------- one-time: split W1c into bf16 hi/lo planes, gl16-ready tiled layout
__global__ __launch_bounds__(256) void k_prep_w1c(
    const float* __restrict__ W1c,
    unsigned short* __restrict__ wch, unsigned short* __restrict__ wcl) {
  const int c = blockIdx.x * 256 + threadIdx.x;
  if (c >= 49152) return;  // 512 rows x 96 chunks
  const int row = c / 96, wc = c - row * 96;
  const int tile = wc >> 2, c4 = wc & 3;
  const int slot = c4 ^ ((row >> 1) & 3);
  const size_t unit = ((size_t)((row >> 7) * 24 + tile) * 128 + (row & 127)) * 4 + slot;
  const float* src = W1c + (size_t)row * IND + wc * 8;
  const float4 f0 = *(const float4*)src, f1 = *(const float4*)(src + 4);
  short8v hi, lo;
  split2(f0, f1, hi, lo);
  *(short8v*)(wch + unit * 8) = hi;
  *(short8v*)(wcl + unit * 8) = lo;
}

// ---------------- init: mask from ctx_len, xh = [target_emb | 0], c=0, lp=0
__global__ __launch_bounds__(256) void k_init(
    const float* __restrict__ te, const int* __restrict__ cl,
    float* __restrict__ mask, float* __restrict__ xh,
    float* __restrict__ cst, float* __restrict__ lp) {
  const int b = blockIdx.x, tid = threadIdx.x;
  const int L = cl[b];
  for (int n = tid; n < NSQ; n += 256) mask[(size_t)b*NSQ + n] = (n >= L) ? NEGV : 0.0f;
  for (int d = tid; d < IND; d += 256) xh[(size_t)b*KXD + d] = te[(size_t)b*IND + d];
  for (int j = tid; j < HIDD; j += 256) {
    xh[(size_t)b*KXD + IND + j] = 0.0f;
    cst[(size_t)b*HIDD + j] = 0.0f;
  }
  if (tid == 0) lp[b] = 0.0f;
}

// ---------------- ctx_part GEMM (R5 verbatim): 2-phase dbuf, XCD-swizzled
__global__ __launch_bounds__(256) void k_ctx5(
    const float* __restrict__ ctx,
    const unsigned short* __restrict__ wch, const unsigned short* __restrict__ wcl,
    const float* __restrict__ bias, const int* __restrict__ clen,
    float* __restrict__ cp) {
  __shared__ __align__(16) unsigned short sWh[2][4096], sWl[2][4096];
  __shared__ __align__(16) unsigned short sCh[2][4096], sCl[2][4096];
  const int bid = blockIdx.x;
  const int v = ((bid & 7) << 9) + (bid >> 3);
  const int mx = v & 3;          // m-block (4)
  const int rbC = v >> 2;        // ctx row-block (1024)
  const int b = rbC >> 3;
  const int nbase = (rbC & 7) << 7;
  if (nbase >= clen[b]) return;
  const int i0 = rbC << 7;
  const int m0 = mx << 7;
  const int tid = threadIdx.x;
  const int lane = tid & 63, wid = tid >> 6;
  const int wm = wid & 1, wn = wid >> 1;
  const int l15 = lane & 15, l4 = lane >> 4;
  const int c0r = tid >> 2, cs = tid & 3;
  const int c1r = 64 + c0r;
  const int k0rd = cs ^ ((c0r >> 1) & 3);
  const int k1rd = cs ^ ((c1r >> 1) & 3);
  const float* csrc0 = ctx + (size_t)(i0 + c0r) * IND + k0rd * 8;
  const float* csrc1 = ctx + (size_t)(i0 + c1r) * IND + k1rd * 8;

#pragma unroll
  for (int i = 0; i < 4; ++i) {
    const int seg = wid * 4 + i;
    const unsigned short* g = ((seg & 8) ? wcl : wch) +
        (size_t)(mx * 24) * 4096 + (seg & 7) * 512 + lane * 8;
    unsigned short* l = ((seg & 8) ? sWl[0] : sWh[0]) + (seg & 7) * 512;
    gl16(g, l);
  }
  {
    short8v hi, lo;
    split2(*(const float4*)csrc0, *(const float4*)(csrc0 + 4), hi, lo);
    *(short8v*)&sCh[0][tid * 8] = hi;
    *(short8v*)&sCl[0][tid * 8] = lo;
    split2(*(const float4*)csrc1, *(const float4*)(csrc1 + 4), hi, lo);
    *(short8v*)&sCh[0][(256 + tid) * 8] = hi;
    *(short8v*)&sCl[0][(256 + tid) * 8] = lo;
  }
  __syncthreads();

  f32x4 acc[4][4] = {};
  for (int t = 0; t < 24; ++t) {
    const int cur = t & 1, nb = cur ^ 1;
    float4 r00, r01, r10, r11;
    if (t + 1 < 24) {
#pragma unroll
      for (int i = 0; i < 4; ++i) {
        const int seg = wid * 4 + i;
        const unsigned short* g = ((seg & 8) ? wcl : wch) +
            (size_t)(mx * 24 + t + 1) * 4096 + (seg & 7) * 512 + lane * 8;
        unsigned short* l = ((seg & 8) ? sWl[nb] : sWh[nb]) + (seg & 7) * 512;
        gl16(g, l);
      }
      r00 = *(const float4*)(csrc0 + (t + 1) * 32);
      r01 = *(const float4*)(csrc0 + (t + 1) * 32 + 4);
      r10 = *(const float4*)(csrc1 + (t + 1) * 32);
      r11 = *(const float4*)(csrc1 + (t + 1) * 32 + 4);
    }
    short8v ah[4], al[4], bh[4], bl[4];
#pragma unroll
    for (int f = 0; f < 4; ++f) {
      const int rw = wm * 64 + f * 16 + l15;
      const int so = (l4 ^ ((rw >> 1) & 3)) << 3;
      ah[f] = *(const short8v*)&sWh[cur][rw * 32 + so];
      al[f] = *(const short8v*)&sWl[cur][rw * 32 + so];
      const int rc = wn * 64 + f * 16 + l15;
      const int sc = (l4 ^ ((rc >> 1) & 3)) << 3;
      bh[f] = *(const short8v*)&sCh[cur][rc * 32 + sc];
      bl[f] = *(const short8v*)&sCl[cur][rc * 32 + sc];
    }
#pragma unroll
    for (int fm = 0; fm < 4; ++fm)
#pragma unroll
      for (int fn = 0; fn < 4; ++fn) {
        acc[fm][fn] = __builtin_amdgcn_mfma_f32_16x16x32_bf16(ah[fm], bh[fn], acc[fm][fn], 0, 0, 0);
        acc[fm][fn] = __builtin_amdgcn_mfma_f32_16x16x32_bf16(ah[fm], bl[fn], acc[fm][fn], 0, 0, 0);
        acc[fm][fn] = __builtin_amdgcn_mfma_f32_16x16x32_bf16(al[fm], bh[fn], acc[fm][fn], 0, 0, 0);
      }
    if (t + 1 < 24) {
      short8v hi, lo;
      split2(r00, r01, hi, lo);
      *(short8v*)&sCh[nb][tid * 8] = hi;
      *(short8v*)&sCl[nb][tid * 8] = lo;
      split2(r10, r11, hi, lo);
      *(short8v*)&sCh[nb][(256 + tid) * 8] = hi;
      *(short8v*)&sCl[nb][(256 + tid) * 8] = lo;
    }
    __syncthreads();
  }
#pragma unroll
  for (int fm = 0; fm < 4; ++fm) {
#pragma unroll
    for (int r = 0; r < 4; ++r) {
      const int m = m0 + wm * 64 + fm * 16 + l4 * 4 + r;
      const float bb = bias[m];
      float* dst = cp + (((size_t)(b * MLPD + m)) << 10) + nbase + wn * 64 + l15;
#pragma unroll
      for (int fn = 0; fn < 4; ++fn)
        dst[fn * 16] = acc[fm][fn][r] + bb;
    }
  }
}

// ---------------- K-split partial GEMM (gates)
__global__ __launch_bounds__(256) void k_pgemm(
    const float* __restrict__ A, int lda, int acol,
    const float* __restrict__ B0, int ldb0, int kb,
    const float* __restrict__ B1, int ldb1,
    int kTiles, int N, float* __restrict__ P) {
  __shared__ float As[16][128];
  __shared__ float Bs[16][132];
  const int n0 = blockIdx.x * 128;
  const int kc0 = blockIdx.y * kTiles * 16;
  const int tid = threadIdx.x;
  const int tn = tid & 15;
  const int ta = tid >> 4;
  float acc[8][8] = {};
  for (int t = 0; t < kTiles; ++t) {
    const int k0 = kc0 + t * 16;
#pragma unroll
    for (int u = 0; u < 2; ++u) {
      const int v = tid + u * 256;
      const int r = v >> 2, kc = v & 3;
      const float4 a4 = *(const float4*)(A + (size_t)r * lda + acol + k0 + kc * 4);
      As[kc*4+0][r] = a4.x; As[kc*4+1][r] = a4.y; As[kc*4+2][r] = a4.z; As[kc*4+3][r] = a4.w;
      const float* bp = (k0 < kb) ? (B0 + (size_t)(n0 + r) * ldb0 + k0 + kc * 4)
                                  : (B1 + (size_t)(n0 + r) * ldb1 + (k0 - kb) + kc * 4);
      const float4 b4 = *(const float4*)bp;
      Bs[kc*4+0][r] = b4.x; Bs[kc*4+1][r] = b4.y; Bs[kc*4+2][r] = b4.z; Bs[kc*4+3][r] = b4.w;
    }
    __syncthreads();
#pragma unroll
    for (int kk = 0; kk < 16; ++kk) {
      float av[8], bv[8];
#pragma unroll
      for (int q = 0; q < 8; ++q) av[q] = As[kk][ta*8+q];
#pragma unroll
      for (int q = 0; q < 8; ++q) bv[q] = Bs[kk][tn*8+q];
#pragma unroll
      for (int ri = 0; ri < 8; ++ri)
#pragma unroll
        for (int ni = 0; ni < 8; ++ni)
          acc[ri][ni] = fmaf(av[ri], bv[ni], acc[ri][ni]);
    }
    __syncthreads();
  }
#pragma unroll
  for (int ri = 0; ri < 8; ++ri) {
    const int i = ta * 8 + ri;
    float* p = P + ((size_t)blockIdx.y * BSZ + i) * N + n0 + tn * 8;
    *(float4*)(p + 0) = make_float4(acc[ri][0], acc[ri][1], acc[ri][2], acc[ri][3]);
    *(float4*)(p + 4) = make_float4(acc[ri][4], acc[ri][5], acc[ri][6], acc[ri][7]);
  }
}

// ---------------- mega step kernel: one block per (b, n-half), 512 threads.
// Phase 1: gate-reduce + LSTM (redundant across halves; half0 writes c & xh-h).
// Phase 2: hproj wave-cooperative (coalesced W1h rows + shfl reduce).
// Phase 3: scores over the n-half (4 m-groups in-block), partial argmax + LSE.
__global__ __launch_bounds__(512) void k_mega(
    const float* __restrict__ gp, const float* __restrict__ b_ih,
    const float* __restrict__ b_hh, const float* __restrict__ W1h,
    const float* __restrict__ w2, const float* __restrict__ b2p,
    const int* __restrict__ clen, float* __restrict__ cst,
    float* __restrict__ xh, const float* __restrict__ cp,
    const float* __restrict__ mask, const float* __restrict__ gum,
    float* __restrict__ part, int step) {
  __shared__ float hs[HIDD];     // h
  __shared__ float hpw[MLPD];    // hproj
  __shared__ float w2s[MLPD];
  __shared__ float4 ps4[4][128]; // per-mgroup partial scores
  __shared__ float rv[128], rs[128], rm[128], r2[128];
  __shared__ int ri[128];
  const int b = blockIdx.x >> 1, half = blockIdx.x & 1;
  const int tid = threadIdx.x;

  // ---- phase 1: gate reduce + LSTM (j = tid)
  {
    float g[4];
#pragma unroll
    for (int q = 0; q < 4; ++q) {
      float s = b_ih[q*HIDD + tid] + b_hh[q*HIDD + tid];
#pragma unroll
      for (int ks = 0; ks < KSG; ++ks)
        s += gp[((size_t)ks*BSZ + b)*G4D + q*HIDD + tid];
      g[q] = s;
    }
    const float c_old = cst[(size_t)b*HIDD + tid];
    const float ig = 1.0f / (1.0f + expf(-g[0]));
    const float fg = 1.0f / (1.0f + expf(-g[1]));
    const float gg = tanhf(g[2]);
    const float og = 1.0f / (1.0f + expf(-g[3]));
    const float cn = fg * c_old + ig * gg;
    const float hn = og * tanhf(cn);
    if (half == 0) {
      cst[(size_t)b*HIDD + tid] = cn;
      xh[(size_t)b*KXD + IND + tid] = hn;
    }
    hs[tid] = hn;
    w2s[tid] = w2[tid];
  }
  __syncthreads();

  // ---- phase 2: hproj, wave-cooperative (wave handles 64 rows; lane owns 32B)
  {
    const int wv = tid >> 6, ln = tid & 63;
    const float4 ha = *(const float4*)&hs[ln*8];
    const float4 hb = *(const float4*)&hs[ln*8+4];
    for (int i = 0; i < 64; ++i) {
      const int row = wv * 64 + i;
      const float* wr = W1h + (size_t)row * HIDD + ln * 8;
      const float4 wa = *(const float4*)wr;
      const float4 wb = *(const float4*)(wr + 4);
      float p = wa.x*ha.x + wa.y*ha.y + wa.z*ha.z + wa.w*ha.w
              + wb.x*hb.x + wb.y*hb.y + wb.z*hb.z + wb.w*hb.w;
#pragma unroll
      for (int o = 1; o < 64; o <<= 1) p += __shfl_xor(p, o);
      if (ln == 0) hpw[row] = p;
    }
  }
  __syncthreads();

  // ---- phase 3: scores over n-half, m-groups in-block
  const int len = clen[b];
  {
    const int mg = tid >> 7;        // m-group 0..3 (128 m each)
    const int nc = tid & 127;       // n-chunk (4 n)
    const int n0 = half * 512 + nc * 4;
    float a0 = 0, a1 = 0, a2 = 0, a3 = 0;
    if (n0 < len) {
      const float* base = cp + ((size_t)(b * MLPD + mg * 128) << 10) + n0;
      const float* hp = &hpw[mg * 128];
      const float* wp = &w2s[mg * 128];
#pragma unroll 8
      for (int mm = 0; mm < 128; ++mm) {
        const float4 c4 = *(const float4*)(base + ((size_t)mm << 10));
        const float h = hp[mm], w = wp[mm];
        a0 = fmaf(tanh_fast(c4.x + h), w, a0);
        a1 = fmaf(tanh_fast(c4.y + h), w, a1);
        a2 = fmaf(tanh_fast(c4.z + h), w, a2);
        a3 = fmaf(tanh_fast(c4.w + h), w, a3);
      }
    }
    ps4[mg][nc] = make_float4(a0, a1, a2, a3);
  }
  __syncthreads();

  // ---- combine m-groups, partial argmax + LSE over this half (threads 0..127)
  float sc[4];
  if (tid < 128) {
    const int n0 = half * 512 + tid * 4;
    if (n0 < len) {
      const float4 p0 = ps4[0][tid], p1 = ps4[1][tid], p2 = ps4[2][tid], p3 = ps4[3][tid];
      const float b2 = b2p[0];
      const float4 m4 = *(const float4*)(mask + (size_t)b * NSQ + n0);
      sc[0] = p0.x + p1.x + p2.x + p3.x + b2 + m4.x;
      sc[1] = p0.y + p1.y + p2.y + p3.y + b2 + m4.y;
      sc[2] = p0.z + p1.z + p2.z + p3.z + b2 + m4.z;
      sc[3] = p0.w + p1.w + p2.w + p3.w + b2 + m4.w;
    } else {
      sc[0] = sc[1] = sc[2] = sc[3] = -1e30f;
    }
    const float4 g4 = *(const float4*)(gum + ((size_t)step * BSZ + b) * NSQ + n0);
    const float gv[4] = {g4.x, g4.y, g4.z, g4.w};
    float bestv = -1e30f, bests = 0.0f, msc = -1e30f;
    int bestn = 0;
#pragma unroll
    for (int q = 0; q < 4; ++q) {
      const float vv = sc[q] + gv[q];
      if (vv > bestv) { bestv = vv; bestn = n0 + q; bests = sc[q]; }
      msc = fmaxf(msc, sc[q]);
    }
    rv[tid] = bestv; ri[tid] = bestn; rs[tid] = bests; rm[tid] = msc;
  }
  __syncthreads();
  for (int o = 64; o > 0; o >>= 1) {
    if (tid < o) {
      if (rv[tid+o] > rv[tid] || (rv[tid+o] == rv[tid] && ri[tid+o] < ri[tid])) {
        rv[tid] = rv[tid+o]; ri[tid] = ri[tid+o]; rs[tid] = rs[tid+o];
      }
      rm[tid] = fmaxf(rm[tid], rm[tid+o]);
    }
    __syncthreads();
  }
  const float M = rm[0];
  if (tid < 128) {
    float se = 0.0f;
#pragma unroll
    for (int q = 0; q < 4; ++q)
      se += __builtin_amdgcn_exp2f((sc[q] - M) * 1.4426950408889634f);
    r2[tid] = se;
  }
  __syncthreads();
  for (int o = 64; o > 0; o >>= 1) {
    if (tid < o) r2[tid] += r2[tid+o];
    __syncthreads();
  }
  if (tid == 0) {
    float* p = part + (size_t)(b * 2 + half) * 8;
    p[0] = rv[0]; p[1] = (float)ri[0]; p[2] = rs[0]; p[3] = M; p[4] = r2[0];
  }
}

// ---------------- pick: combine halves, LSE merge, lp/mask/out, x feedback
__global__ __launch_bounds__(192) void k_pick(
    const float* __restrict__ part, float* __restrict__ mask,
    float* __restrict__ lp, const float* __restrict__ ctx,
    float* __restrict__ xh, float* __restrict__ outv, int step) {
  const int b = blockIdx.x, tid = threadIdx.x;
  __shared__ int sel;
  if (tid == 0) {
    const float* p0 = part + (size_t)(b * 2) * 8;
    const float* p1 = p0 + 8;
    int n; float bests;
    if (p1[0] > p0[0]) { n = (int)p1[1]; bests = p1[2]; }
    else               { n = (int)p0[1]; bests = p0[2]; }
    const float M0 = p0[3], M1 = p1[3];
    const float M = fmaxf(M0, M1);
    const float S = p0[4] * expf(M0 - M) + p1[4] * expf(M1 - M);
    const float nlp = lp[b] + bests - (M + logf(S));
    lp[b] = nlp;
    mask[(size_t)b * NSQ + n] = NEGV;
    outv[step * BSZ + b] = (float)n;
    if (step == NSTEPC - 1) outv[NSTEPC * BSZ + b] = nlp;
    sel = n;
  }
  __syncthreads();
  const int n = sel;
  const float4* src = (const float4*)(ctx + ((size_t)b * NSQ + n) * IND);
  float4* dst = (float4*)(xh + (size_t)b * KXD);
  dst[tid] = src[tid];   // 192 threads x 16B = 768 floats
}

extern "C" void kernel_launch(void* const* d_in, const int* in_sizes, int n_in,
                              void* d_out, int out_size, void* d_ws, size_t ws_size,
                              hipStream_t stream) {
  const float* target_emb = (const float*)d_in[0];
  const float* ctx_emb   = (const float*)d_in[1];
  const int*   ctx_len   = (const int*)d_in[3];
  const float* W_ih = (const float*)d_in[5];
  const float* W_hh = (const float*)d_in[6];
  const float* b_ih = (const float*)d_in[7];
  const float* b_hh = (const float*)d_in[8];
  const float* W1c  = (const float*)d_in[9];
  const float* W1h  = (const float*)d_in[10];
  const float* b1   = (const float*)d_in[11];
  const float* w2   = (const float*)d_in[12];
  const float* b2   = (const float*)d_in[13];
  const float* gumbel = (const float*)d_in[14];
  float* out = (float*)d_out;

  float* ws = (float*)d_ws;
  size_t off = 0;
  auto alloc = [&](size_t n) { float* p = ws + off; off += (n + 63) & ~(size_t)63; return p; };

  float* cp   = alloc((size_t)BSZ * MLPD * NSQ);   // 268 MB
  float* gp   = alloc((size_t)KSG * BSZ * G4D);
  float* mask = alloc((size_t)BSZ * NSQ);
  float* xh   = alloc((size_t)BSZ * KXD);
  float* cst  = alloc((size_t)BSZ * HIDD);
  float* lp   = alloc(128);
  float* part = alloc(BSZ * 2 * 8);
  unsigned short* wch = (unsigned short*)alloc(196608);   // 512x768 u16
  unsigned short* wcl = (unsigned short*)alloc(196608);

  k_prep_w1c<<<192, 256, 0, stream>>>(W1c, wch, wcl);
  k_init<<<BSZ, 256, 0, stream>>>(target_emb, ctx_len, mask, xh, cst, lp);
  k_ctx5<<<4096, 256, 0, stream>>>(ctx_emb, wch, wcl, b1, ctx_len, cp);

  for (int t = 0; t < NSTEPC; ++t) {
    k_pgemm<<<dim3(G4D/128, KSG), 256, 0, stream>>>(
        xh, KXD, 0, W_ih, IND, IND, W_hh, HIDD, 5, G4D, gp);
    k_mega<<<BSZ * 2, 512, 0, stream>>>(
        gp, b_ih, b_hh, W1h, w2, b2, ctx_len, cst, xh, cp, mask,
        gumbel, part, t);
    k_pick<<<BSZ, 192, 0, stream>>>(part, mask, lp, ctx_emb, xh, out, t);
  }
}

// Round 10
// 864.336 us; speedup vs baseline: 1.1625x; 1.1625x over previous
//
#include <hip/hip_runtime.h>
#include <hip/hip_bf16.h>

#define BSZ 128
#define NSQ 1024
#define NSTEPC 8
#define IND 768
#define HIDD 512
#define G4D 2048
#define MLPD 512
#define KXD 1280
#define NEGV -100000.0f
#define KSG 16   // K-split chunks for gates gemm (1280/16 = 80 = 5 tiles)
#define KSH 8    // K-split chunks for hproj gemm (512/8 = 64 = 4 tiles)
#define MSPLIT 4 // m-split for scores kernel

typedef __attribute__((ext_vector_type(4))) float f32x4;
typedef __attribute__((ext_vector_type(8))) short short8v;

__device__ __forceinline__ void split2(float4 f0, float4 f1, short8v& hi, short8v& lo) {
  float fv[8] = {f0.x, f0.y, f0.z, f0.w, f1.x, f1.y, f1.z, f1.w};
#pragma unroll
  for (int j = 0; j < 8; ++j) {
    const unsigned ub = __builtin_bit_cast(unsigned, fv[j]);
    const unsigned hb = ub & 0xFFFF0000u;
    const float lf = fv[j] - __builtin_bit_cast(float, hb);
    hi[j] = (short)(hb >> 16);
    lo[j] = (short)(__builtin_bit_cast(unsigned, lf) >> 16);
  }
}

// tanh(x) = 1 - 2/(e^{2x}+1)
__device__ __forceinline__ float tanh_fast(float x) {
  x = fminf(fmaxf(x, -15.0f), 15.0f);
  float e = __builtin_amdgcn_exp2f(x * 2.8853900817779268f);
  float r = __builtin_amdgcn_rcpf(e + 1.0f);
  return fmaf(-2.0f, r, 1.0f);
}

// ---------------- one-time: split W1c into FRAGMENT-ORDER bf16 hi/lo planes.
// unit16B = (((mx*2+wm)*24 + t)*4 + f)*64 + l4*16 + l15
__global__ __launch_bounds__(256) void k_prep_wfrag(
    const float* __restrict__ W1c,
    unsigned short* __restrict__ wfh, unsigned short* __restrict__ wfl) {
  const int c = blockIdx.x * 256 + threadIdx.x;
  if (c >= 49152) return;  // 512 rows x 96 chunks of 8 k-elements
  const int row = c / 96, wc = c - row * 96;
  const int mxwm = row >> 6;
  const int f = (row >> 4) & 3, l15 = row & 15;
  const int t = wc >> 2, l4 = wc & 3;
  const size_t unit = (((size_t)(mxwm * 24 + t) * 4 + f) * 64) + l4 * 16 + l15;
  const float* src = W1c + (size_t)row * IND + wc * 8;
  const float4 f0 = *(const float4*)src, f1 = *(const float4*)(src + 4);
  short8v hi, lo;
  split2(f0, f1, hi, lo);
  *(short8v*)(wfh + unit * 8) = hi;
  *(short8v*)(wfl + unit * 8) = lo;
}

// ---------------- init: mask from ctx_len, xh = [target_emb | 0], c=0, lp=0
__global__ __launch_bounds__(256) void k_init(
    const float* __restrict__ te, const int* __restrict__ cl,
    float* __restrict__ mask, float* __restrict__ xh,
    float* __restrict__ cst, float* __restrict__ lp) {
  const int b = blockIdx.x, tid = threadIdx.x;
  const int L = cl[b];
  for (int n = tid; n < NSQ; n += 256) mask[(size_t)b*NSQ + n] = (n >= L) ? NEGV : 0.0f;
  for (int d = tid; d < IND; d += 256) xh[(size_t)b*KXD + d] = te[(size_t)b*IND + d];
  for (int j = tid; j < HIDD; j += 256) {
    xh[(size_t)b*KXD + IND + j] = 0.0f;
    cst[(size_t)b*HIDD + j] = 0.0f;
  }
  if (tid == 0) lp[b] = 0.0f;
}

// ---------------- ctx GEMM, register-pipelined, LDS/barrier-free:
// cp[b][m][n] = sum_k ctx[b,n,k]*W1c[m,k] + b1[m]; split-bf16 (hh+hl+lh)
// 4096 blocks (XCD-swizzled, mask early-exit), 256 thr / 4 independent waves.
// Full register double-buffer: tile t+1 loads in flight during tile t's MFMAs.
struct TileRegs {
  short8v wh[4], wl[4];   // W hi/lo frags (already bf16 planes)
  float4 ca[4], cb[4];    // ctx f32 (split in do_tile)
};

__device__ __forceinline__ void ld_tile(
    TileRegs& T, const unsigned short* __restrict__ wfh,
    const unsigned short* __restrict__ wfl, size_t wbase,
    const float* __restrict__ cbase, int t) {
  const size_t toff = wbase + (size_t)t * 2048;
#pragma unroll
  for (int f = 0; f < 4; ++f) {
    T.wh[f] = *(const short8v*)(wfh + toff + f * 512);
    T.wl[f] = *(const short8v*)(wfl + toff + f * 512);
    const float* s = cbase + (size_t)(f * 16) * IND + t * 32;
    T.ca[f] = *(const float4*)s;
    T.cb[f] = *(const float4*)(s + 4);
  }
}

__device__ __forceinline__ void do_tile(TileRegs& T, f32x4 acc[4][4]) {
  short8v bh[4], bl[4];
#pragma unroll
  for (int f = 0; f < 4; ++f) split2(T.ca[f], T.cb[f], bh[f], bl[f]);
  __builtin_amdgcn_s_setprio(1);
#pragma unroll
  for (int fm = 0; fm < 4; ++fm)
#pragma unroll
    for (int fn = 0; fn < 4; ++fn) {
      acc[fm][fn] = __builtin_amdgcn_mfma_f32_16x16x32_bf16(T.wh[fm], bh[fn], acc[fm][fn], 0, 0, 0);
      acc[fm][fn] = __builtin_amdgcn_mfma_f32_16x16x32_bf16(T.wh[fm], bl[fn], acc[fm][fn], 0, 0, 0);
      acc[fm][fn] = __builtin_amdgcn_mfma_f32_16x16x32_bf16(T.wl[fm], bh[fn], acc[fm][fn], 0, 0, 0);
    }
  __builtin_amdgcn_s_setprio(0);
}

__global__ __launch_bounds__(256, 2) void k_ctx8(
    const float* __restrict__ ctx,
    const unsigned short* __restrict__ wfh, const unsigned short* __restrict__ wfl,
    const float* __restrict__ bias, const int* __restrict__ clen,
    float* __restrict__ cp) {
  // bijective XCD swizzle: all 4 m-blocks of a ctx row-block share one XCD's L2
  const int bid = blockIdx.x;
  const int v = ((bid & 7) << 9) + (bid >> 3);
  const int mx = v & 3;          // m-block (4)
  const int rbC = v >> 2;        // ctx row-block (1024)
  const int b = rbC >> 3;
  const int nbase = (rbC & 7) << 7;
  if (nbase >= clen[b]) return;  // masked region: cp never read there
  const int i0 = rbC << 7;
  const int m0 = mx << 7;
  const int tid = threadIdx.x;
  const int lane = tid & 63, wid = tid >> 6;
  const int wm = wid & 1, wn = wid >> 1;
  const int l15 = lane & 15, l4 = lane >> 4;

  const size_t wbase = (size_t)((mx * 2 + wm) * 24) * 2048 + lane * 8;
  const float* cbase = ctx + (size_t)(i0 + wn * 64 + l15) * IND + l4 * 8;

  f32x4 acc[4][4] = {};  // [fm][fn]
  TileRegs A, B;
  ld_tile(A, wfh, wfl, wbase, cbase, 0);
  for (int t = 0; t < 24; t += 2) {
    ld_tile(B, wfh, wfl, wbase, cbase, t + 1);  // t+1 <= 23 always (24 even)
    do_tile(A, acc);
    if (t + 2 < 24) ld_tile(A, wfh, wfl, wbase, cbase, t + 2);
    do_tile(B, acc);
  }
  // epilogue: D row m = (l>>4)*4 + reg, col n = l&15 (16-lane 64B segments)
#pragma unroll
  for (int fm = 0; fm < 4; ++fm) {
#pragma unroll
    for (int r = 0; r < 4; ++r) {
      const int m = m0 + wm * 64 + fm * 16 + l4 * 4 + r;
      const float bb = bias[m];
      float* dst = cp + (((size_t)(b * MLPD + m)) << 10) + nbase + wn * 64 + l15;
#pragma unroll
      for (int fn = 0; fn < 4; ++fn)
        dst[fn * 16] = acc[fm][fn][r] + bb;
    }
  }
}

// ---------------- K-split partial GEMM: P[kc][i][n] = sum_{k in chunk} A[i,k]*B(n,k)
__global__ __launch_bounds__(256) void k_pgemm(
    const float* __restrict__ A, int lda, int acol,
    const float* __restrict__ B0, int ldb0, int kb,
    const float* __restrict__ B1, int ldb1,
    int kTiles, int N, float* __restrict__ P) {
  __shared__ float As[16][128];
  __shared__ float Bs[16][132];
  const int n0 = blockIdx.x * 128;
  const int kc0 = blockIdx.y * kTiles * 16;
  const int tid = threadIdx.x;
  const int tn = tid & 15;   // n-group
  const int ta = tid >> 4;   // i-group
  float acc[8][8] = {};      // [ri][ni]
  for (int t = 0; t < kTiles; ++t) {
    const int k0 = kc0 + t * 16;
#pragma unroll
    for (int u = 0; u < 2; ++u) {
      const int v = tid + u * 256;
      const int r = v >> 2, kc = v & 3;
      const float4 a4 = *(const float4*)(A + (size_t)r * lda + acol + k0 + kc * 4);
      As[kc*4+0][r] = a4.x; As[kc*4+1][r] = a4.y; As[kc*4+2][r] = a4.z; As[kc*4+3][r] = a4.w;
      const float* bp = (k0 < kb) ? (B0 + (size_t)(n0 + r) * ldb0 + k0 + kc * 4)
                                  : (B1 + (size_t)(n0 + r) * ldb1 + (k0 - kb) + kc * 4);
      const float4 b4 = *(const float4*)bp;
      Bs[kc*4+0][r] = b4.x; Bs[kc*4+1][r] = b4.y; Bs[kc*4+2][r] = b4.z; Bs[kc*4+3][r] = b4.w;
    }
    __syncthreads();
#pragma unroll
    for (int kk = 0; kk < 16; ++kk) {
      float av[8], bv[8];
#pragma unroll
      for (int q = 0; q < 8; ++q) av[q] = As[kk][ta*8+q];
#pragma unroll
      for (int q = 0; q < 8; ++q) bv[q] = Bs[kk][tn*8+q];
#pragma unroll
      for (int ri = 0; ri < 8; ++ri)
#pragma unroll
        for (int ni = 0; ni < 8; ++ni)
          acc[ri][ni] = fmaf(av[ri], bv[ni], acc[ri][ni]);
    }
    __syncthreads();
  }
#pragma unroll
  for (int ri = 0; ri < 8; ++ri) {
    const int i = ta * 8 + ri;
    float* p = P + ((size_t)blockIdx.y * BSZ + i) * N + n0 + tn * 8;
    *(float4*)(p + 0) = make_float4(acc[ri][0], acc[ri][1], acc[ri][2], acc[ri][3]);
    *(float4*)(p + 4) = make_float4(acc[ri][4], acc[ri][5], acc[ri][6], acc[ri][7]);
  }
}

// ---------------- reduce gate partials + LSTM cell update (writes c, xh h-part)
__global__ __launch_bounds__(512) void k_lstm(
    const float* __restrict__ gp, const float* __restrict__ b_ih,
    const float* __restrict__ b_hh, float* __restrict__ cst, float* __restrict__ xh) {
  const int b = blockIdx.x, j = threadIdx.x;
  float g[4];
#pragma unroll
  for (int q = 0; q < 4; ++q) {
    float s = b_ih[q*HIDD + j] + b_hh[q*HIDD + j];
#pragma unroll
    for (int ks = 0; ks < KSG; ++ks) s += gp[((size_t)ks*BSZ + b)*G4D + q*HIDD + j];
    g[q] = s;
  }
  const float c_old = cst[(size_t)b*HIDD + j];
  const float ig = 1.0f / (1.0f + expf(-g[0]));
  const float fg = 1.0f / (1.0f + expf(-g[1]));
  const float gg = tanhf(g[2]);
  const float og = 1.0f / (1.0f + expf(-g[3]));
  const float cn = fg * c_old + ig * gg;
  const float hn = og * tanhf(cn);
  cst[(size_t)b*HIDD + j] = cn;
  xh[(size_t)b*KXD + IND + j] = hn;
}

// ---------------- scores partial: psc[b][mh][n] = sum_{m in mh-range} tanh(cp+hp)*w2
__global__ __launch_bounds__(256) void k_scores(
    const float* __restrict__ cp, const float* __restrict__ hpp,
    const float* __restrict__ w2, const int* __restrict__ clen,
    float* __restrict__ psc) {
  const int mh = blockIdx.x;  // [0,MSPLIT)
  const int b = blockIdx.y;
  const int tid = threadIdx.x;
  __shared__ float hs[128], ws[128];
  if (tid < 128) {
    const int m = mh * 128 + tid;
    float s = 0.0f;
#pragma unroll
    for (int ks = 0; ks < KSH; ++ks) s += hpp[((size_t)ks*BSZ + b)*MLPD + m];
    hs[tid] = s;
    ws[tid] = w2[m];
  }
  __syncthreads();
  const int len = clen[b];
  const int n0 = tid * 4;
  if (n0 >= len) return;
  float ax = 0, ay = 0, az = 0, aw = 0;
  const float* base = cp + ((size_t)b * MLPD + mh * 128) * NSQ + n0;
#pragma unroll 4
  for (int mm = 0; mm < 128; ++mm) {
    const float4 c4 = *(const float4*)(base + (size_t)mm * NSQ);
    const float h = hs[mm], w = ws[mm];
    ax = fmaf(tanh_fast(c4.x + h), w, ax);
    ay = fmaf(tanh_fast(c4.y + h), w, ay);
    az = fmaf(tanh_fast(c4.z + h), w, az);
    aw = fmaf(tanh_fast(c4.w + h), w, aw);
  }
  *(float4*)(psc + ((size_t)b * MSPLIT + mh) * NSQ + n0) = make_float4(ax, ay, az, aw);
}

// ---------------- argmax + LSE + lp + mask/x update (one block per batch row)
__global__ __launch_bounds__(256) void k_argmax(
    const float* __restrict__ psc, float* __restrict__ mask,
    const float* __restrict__ gum, const float* __restrict__ b2p,
    float* __restrict__ lp, const float* __restrict__ ctx,
    float* __restrict__ xh, float* __restrict__ outv, int step) {
  const int b = blockIdx.x, tid = threadIdx.x;
  __shared__ float rv[256], rs[256], rm[256];
  __shared__ int ri[256];
  __shared__ int sel;
  const float b2 = b2p[0];
  const int n0 = tid * 4;
  const float4 m4 = *(const float4*)(mask + (size_t)b * NSQ + n0);
  float sc[4] = {b2 + m4.x, b2 + m4.y, b2 + m4.z, b2 + m4.w};
#pragma unroll
  for (int mh = 0; mh < MSPLIT; ++mh) {
    const float4 p4 = *(const float4*)(psc + ((size_t)b * MSPLIT + mh) * NSQ + n0);
    sc[0] += p4.x; sc[1] += p4.y; sc[2] += p4.z; sc[3] += p4.w;
  }
  const float4 g4 = *(const float4*)(gum + ((size_t)step * BSZ + b) * NSQ + n0);
  const float gv[4] = {g4.x, g4.y, g4.z, g4.w};
  float bestv = -1e30f, bests = 0.0f, msc = -1e30f;
  int bestn = 0;
#pragma unroll
  for (int q = 0; q < 4; ++q) {
    const float v = sc[q] + gv[q];
    if (v > bestv) { bestv = v; bestn = n0 + q; bests = sc[q]; }
    msc = fmaxf(msc, sc[q]);
  }
  rv[tid] = bestv; ri[tid] = bestn; rs[tid] = bests; rm[tid] = msc;
  __syncthreads();
  for (int o = 128; o > 0; o >>= 1) {
    if (tid < o) {
      if (rv[tid+o] > rv[tid] || (rv[tid+o] == rv[tid] && ri[tid+o] < ri[tid])) {
        rv[tid] = rv[tid+o]; ri[tid] = ri[tid+o]; rs[tid] = rs[tid+o];
      }
      rm[tid] = fmaxf(rm[tid], rm[tid+o]);
    }
    __syncthreads();
  }
  const float M = rm[0];
  __syncthreads();
  float se = 0.0f;
#pragma unroll
  for (int q = 0; q < 4; ++q)
    se += __builtin_amdgcn_exp2f((sc[q] - M) * 1.4426950408889634f);
  rm[tid] = se;
  __syncthreads();
  for (int o = 128; o > 0; o >>= 1) {
    if (tid < o) rm[tid] += rm[tid+o];
    __syncthreads();
  }
  if (tid == 0) {
    const int n = ri[0];
    const float lse = M + logf(rm[0]);
    const float nlp = lp[b] + rs[0] - lse;
    lp[b] = nlp;
    mask[(size_t)b * NSQ + n] = NEGV;
    outv[step * BSZ + b] = (float)n;
    if (step == NSTEPC - 1) outv[NSTEPC * BSZ + b] = nlp;
    sel = n;
  }
  __syncthreads();
  const int n = sel;
  const float4* src = (const float4*)(ctx + ((size_t)b * NSQ + n) * IND);
  float4* dst = (float4*)(xh + (size_t)b * KXD);
  for (int d = tid; d < IND / 4; d += 256) dst[d] = src[d];
}

extern "C" void kernel_launch(void* const* d_in, const int* in_sizes, int n_in,
                              void* d_out, int out_size, void* d_ws, size_t ws_size,
                              hipStream_t stream) {
  const float* target_emb = (const float*)d_in[0];
  const float* ctx_emb   = (const float*)d_in[1];
  const int*   ctx_len   = (const int*)d_in[3];
  const float* W_ih = (const float*)d_in[5];
  const float* W_hh = (const float*)d_in[6];
  const float* b_ih = (const float*)d_in[7];
  const float* b_hh = (const float*)d_in[8];
  const float* W1c  = (const float*)d_in[9];
  const float* W1h  = (const float*)d_in[10];
  const float* b1   = (const float*)d_in[11];
  const float* w2   = (const float*)d_in[12];
  const float* b2   = (const float*)d_in[13];
  const float* gumbel = (const float*)d_in[14];
  float* out = (float*)d_out;

  float* ws = (float*)d_ws;
  size_t off = 0;
  auto alloc = [&](size_t n) { float* p = ws + off; off += (n + 63) & ~(size_t)63; return p; };

  float* cp   = alloc((size_t)BSZ * MLPD * NSQ);   // 268 MB
  float* gp   = alloc((size_t)KSG * BSZ * G4D);
  float* hpp  = alloc((size_t)KSH * BSZ * MLPD);
  float* psc  = alloc((size_t)BSZ * MSPLIT * NSQ);
  float* mask = alloc((size_t)BSZ * NSQ);
  float* xh   = alloc((size_t)BSZ * KXD);
  float* cst  = alloc((size_t)BSZ * HIDD);
  float* lp   = alloc(128);
  unsigned short* wfh = (unsigned short*)alloc(196608);   // 512x768 u16, frag-order
  unsigned short* wfl = (unsigned short*)alloc(196608);

  k_prep_wfrag<<<192, 256, 0, stream>>>(W1c, wfh, wfl);
  k_init<<<BSZ, 256, 0, stream>>>(target_emb, ctx_len, mask, xh, cst, lp);
  k_ctx8<<<4096, 256, 0, stream>>>(ctx_emb, wfh, wfl, b1, ctx_len, cp);

  for (int t = 0; t < NSTEPC; ++t) {
    // gates partials: N=2048, K=1280 split in 16 chunks of 5 tiles
    k_pgemm<<<dim3(G4D/128, KSG), 256, 0, stream>>>(
        xh, KXD, 0, W_ih, IND, IND, W_hh, HIDD, 5, G4D, gp);
    k_lstm<<<BSZ, 512, 0, stream>>>(gp, b_ih, b_hh, cst, xh);
    // hproj partials: N=512, K=512 split in 8 chunks of 4 tiles
    k_pgemm<<<dim3(MLPD/128, KSH), 256, 0, stream>>>(
        xh, KXD, IND, W1h, HIDD, 1 << 30, nullptr, 0, 4, MLPD, hpp);
    k_scores<<<dim3(MSPLIT, BSZ), 256, 0, stream>>>(cp, hpp, w2, ctx_len, psc);
    k_argmax<<<BSZ, 256, 0, stream>>>(psc, mask, gumbel, b2, lp, ctx_emb, xh, out, t);
  }
}

// Round 11
// 857.014 us; speedup vs baseline: 1.1724x; 1.0085x over previous
//
#include <hip/hip_runtime.h>
#include <hip/hip_bf16.h>

#define BSZ 128
#define NSQ 1024
#define NSTEPC 8
#define IND 768
#define HIDD 512
#define G4D 2048
#define MLPD 512
#define KXD 1280
#define NEGV -100000.0f
#define KSG 16   // K-split chunks for gates gemm (1280/16 = 80 = 5 tiles)
#define KSH 8    // K-split chunks for hproj gemm (512/8 = 64 = 4 tiles)
#define MSPLIT 4 // m-split for scores kernel

typedef __attribute__((ext_vector_type(4))) float f32x4;
typedef __attribute__((ext_vector_type(8))) short short8v;

__device__ __forceinline__ void split2(float4 f0, float4 f1, short8v& hi, short8v& lo) {
  float fv[8] = {f0.x, f0.y, f0.z, f0.w, f1.x, f1.y, f1.z, f1.w};
#pragma unroll
  for (int j = 0; j < 8; ++j) {
    const unsigned ub = __builtin_bit_cast(unsigned, fv[j]);
    const unsigned hb = ub & 0xFFFF0000u;
    const float lf = fv[j] - __builtin_bit_cast(float, hb);
    hi[j] = (short)(hb >> 16);
    lo[j] = (short)(__builtin_bit_cast(unsigned, lf) >> 16);
  }
}

// tanh(x) = 1 - 2/(e^{2x}+1)
__device__ __forceinline__ float tanh_fast(float x) {
  x = fminf(fmaxf(x, -15.0f), 15.0f);
  float e = __builtin_amdgcn_exp2f(x * 2.8853900817779268f);
  float r = __builtin_amdgcn_rcpf(e + 1.0f);
  return fmaf(-2.0f, r, 1.0f);
}

// ---------------- one-time: split W1c into FRAGMENT-ORDER bf16 hi/lo planes.
// wave w = row>>6 (8 waves = m 0..511), frag f=(row>>4)&3, l15=row&15,
// tile t=k>>5, l4=(k>>3)&3. unit16B = ((w*24 + t)*4 + f)*64 + l4*16 + l15
__global__ __launch_bounds__(256) void k_prep_wfrag(
    const float* __restrict__ W1c,
    unsigned short* __restrict__ wfh, unsigned short* __restrict__ wfl) {
  const int c = blockIdx.x * 256 + threadIdx.x;
  if (c >= 49152) return;  // 512 rows x 96 chunks of 8 k-elements
  const int row = c / 96, wc = c - row * 96;
  const int w = row >> 6;
  const int f = (row >> 4) & 3, l15 = row & 15;
  const int t = wc >> 2, l4 = wc & 3;
  const size_t unit = (((size_t)(w * 24 + t) * 4 + f) * 64) + l4 * 16 + l15;
  const float* src = W1c + (size_t)row * IND + wc * 8;
  const float4 f0 = *(const float4*)src, f1 = *(const float4*)(src + 4);
  short8v hi, lo;
  split2(f0, f1, hi, lo);
  *(short8v*)(wfh + unit * 8) = hi;
  *(short8v*)(wfl + unit * 8) = lo;
}

// ---------------- init: mask from ctx_len, xh = [target_emb | 0], c=0, lp=0
__global__ __launch_bounds__(256) void k_init(
    const float* __restrict__ te, const int* __restrict__ cl,
    float* __restrict__ mask, float* __restrict__ xh,
    float* __restrict__ cst, float* __restrict__ lp) {
  const int b = blockIdx.x, tid = threadIdx.x;
  const int L = cl[b];
  for (int n = tid; n < NSQ; n += 256) mask[(size_t)b*NSQ + n] = (n >= L) ? NEGV : 0.0f;
  for (int d = tid; d < IND; d += 256) xh[(size_t)b*KXD + d] = te[(size_t)b*IND + d];
  for (int j = tid; j < HIDD; j += 256) {
    xh[(size_t)b*KXD + IND + j] = 0.0f;
    cst[(size_t)b*HIDD + j] = 0.0f;
  }
  if (tid == 0) lp[b] = 0.0f;
}

// ---------------- ctx GEMM, BM=512 (full M per block) x BN=128:
// minimizes memory-path bytes: ctx read ONCE (393KB/block), W once (1.57MB,
// L2-resident frag-order planes, direct global->VGPR). 512 thr / 8 waves;
// wave w owns m[w*64, w*64+64) x n[0,128): acc 4x8 f32x4. ctx split once
// into XOR-swizzled LDS planes (16KB/tile, double-buffered, 1 barrier/tile
// with no outstanding loads at the drain). 96 MFMA/tile/wave.
__global__ __launch_bounds__(512, 1) void k_ctx9(
    const float* __restrict__ ctx,
    const unsigned short* __restrict__ wfh, const unsigned short* __restrict__ wfl,
    const float* __restrict__ bias, const int* __restrict__ clen,
    float* __restrict__ cp) {
  __shared__ __align__(16) unsigned short sCh[2][4096], sCl[2][4096];  // 128r x 32k planes
  const int strip = blockIdx.x;          // 1024 n-strips
  const int b = strip >> 3;
  const int nbase = (strip & 7) << 7;
  if (nbase >= clen[b]) return;          // masked region: cp never read there
  const int i0 = strip << 7;
  const int tid = threadIdx.x;
  const int lane = tid & 63, wid = tid >> 6;
  const int l15 = lane & 15, l4 = lane >> 4;
  // ctx staging: 512 chunks (128 rows x 4 k-slots), 1 per thread, pre-swizzled src
  const int crow = tid >> 2, cs = tid & 3;
  const int kread = cs ^ ((crow >> 1) & 3);
  const float* csrc = ctx + (size_t)(i0 + crow) * IND + kread * 8;
  // W frag base (shorts): ((wid*24 + t)*4 + f)*512 + lane*8
  const size_t wbase = (size_t)(wid * 24) * 2048 + lane * 8;

  // prologue: stage tile 0 ctx planes
  {
    short8v hi, lo;
    split2(*(const float4*)csrc, *(const float4*)(csrc + 4), hi, lo);
    *(short8v*)&sCh[0][tid * 8] = hi;
    *(short8v*)&sCl[0][tid * 8] = lo;
  }

  f32x4 acc[4][8] = {};  // [fm][fn]
  for (int t = 0; t < 24; ++t) {
    __syncthreads();                       // buf[t&1] ready; nothing outstanding
    const int cur = t & 1;
    float4 q0, q1;
    if (t + 1 < 24) {                      // prefetch next ctx chunk (regs)
      q0 = *(const float4*)(csrc + (t + 1) * 32);
      q1 = *(const float4*)(csrc + (t + 1) * 32 + 4);
    }
    // W frags for this tile: direct coalesced loads (each byte read once)
    short8v wh[4], wl[4];
    const size_t toff = wbase + (size_t)t * 2048;
#pragma unroll
    for (int f = 0; f < 4; ++f) {
      wh[f] = *(const short8v*)(wfh + toff + f * 512);
      wl[f] = *(const short8v*)(wfl + toff + f * 512);
    }
#pragma unroll
    for (int fn = 0; fn < 8; ++fn) {
      const int rc = fn * 16 + l15;
      const int so = (l4 ^ ((rc >> 1) & 3)) << 3;
      const short8v bhv = *(const short8v*)&sCh[cur][rc * 32 + so];
      const short8v blv = *(const short8v*)&sCl[cur][rc * 32 + so];
      __builtin_amdgcn_s_setprio(1);
#pragma unroll
      for (int fm = 0; fm < 4; ++fm) {
        acc[fm][fn] = __builtin_amdgcn_mfma_f32_16x16x32_bf16(wh[fm], bhv, acc[fm][fn], 0, 0, 0);
        acc[fm][fn] = __builtin_amdgcn_mfma_f32_16x16x32_bf16(wh[fm], blv, acc[fm][fn], 0, 0, 0);
        acc[fm][fn] = __builtin_amdgcn_mfma_f32_16x16x32_bf16(wl[fm], bhv, acc[fm][fn], 0, 0, 0);
      }
      __builtin_amdgcn_s_setprio(0);
    }
    if (t + 1 < 24) {                      // split + write next buffer (disjoint)
      short8v hi, lo;
      split2(q0, q1, hi, lo);
      *(short8v*)&sCh[cur ^ 1][tid * 8] = hi;
      *(short8v*)&sCl[cur ^ 1][tid * 8] = lo;
    }
  }
  // epilogue: m = wid*64 + fm*16 + l4*4 + r, n = nbase + fn*16 + l15
#pragma unroll
  for (int fm = 0; fm < 4; ++fm) {
#pragma unroll
    for (int r = 0; r < 4; ++r) {
      const int m = wid * 64 + fm * 16 + l4 * 4 + r;
      const float bb = bias[m];
      float* dst = cp + (((size_t)(b * MLPD + m)) << 10) + nbase + l15;
#pragma unroll
      for (int fn = 0; fn < 8; ++fn)
        dst[fn * 16] = acc[fm][fn][r] + bb;
    }
  }
}

// ---------------- K-split partial GEMM: P[kc][i][n] = sum_{k in chunk} A[i,k]*B(n,k)
__global__ __launch_bounds__(256) void k_pgemm(
    const float* __restrict__ A, int lda, int acol,
    const float* __restrict__ B0, int ldb0, int kb,
    const float* __restrict__ B1, int ldb1,
    int kTiles, int N, float* __restrict__ P) {
  __shared__ float As[16][128];
  __shared__ float Bs[16][132];
  const int n0 = blockIdx.x * 128;
  const int kc0 = blockIdx.y * kTiles * 16;
  const int tid = threadIdx.x;
  const int tn = tid & 15;   // n-group
  const int ta = tid >> 4;   // i-group
  float acc[8][8] = {};      // [ri][ni]
  for (int t = 0; t < kTiles; ++t) {
    const int k0 = kc0 + t * 16;
#pragma unroll
    for (int u = 0; u < 2; ++u) {
      const int v = tid + u * 256;
      const int r = v >> 2, kc = v & 3;
      const float4 a4 = *(const float4*)(A + (size_t)r * lda + acol + k0 + kc * 4);
      As[kc*4+0][r] = a4.x; As[kc*4+1][r] = a4.y; As[kc*4+2][r] = a4.z; As[kc*4+3][r] = a4.w;
      const float* bp = (k0 < kb) ? (B0 + (size_t)(n0 + r) * ldb0 + k0 + kc * 4)
                                  : (B1 + (size_t)(n0 + r) * ldb1 + (k0 - kb) + kc * 4);
      const float4 b4 = *(const float4*)bp;
      Bs[kc*4+0][r] = b4.x; Bs[kc*4+1][r] = b4.y; Bs[kc*4+2][r] = b4.z; Bs[kc*4+3][r] = b4.w;
    }
    __syncthreads();
#pragma unroll
    for (int kk = 0; kk < 16; ++kk) {
      float av[8], bv[8];
#pragma unroll
      for (int q = 0; q < 8; ++q) av[q] = As[kk][ta*8+q];
#pragma unroll
      for (int q = 0; q < 8; ++q) bv[q] = Bs[kk][tn*8+q];
#pragma unroll
      for (int ri = 0; ri < 8; ++ri)
#pragma unroll
        for (int ni = 0; ni < 8; ++ni)
          acc[ri][ni] = fmaf(av[ri], bv[ni], acc[ri][ni]);
    }
    __syncthreads();
  }
#pragma unroll
  for (int ri = 0; ri < 8; ++ri) {
    const int i = ta * 8 + ri;
    float* p = P + ((size_t)blockIdx.y * BSZ + i) * N + n0 + tn * 8;
    *(float4*)(p + 0) = make_float4(acc[ri][0], acc[ri][1], acc[ri][2], acc[ri][3]);
    *(float4*)(p + 4) = make_float4(acc[ri][4], acc[ri][5], acc[ri][6], acc[ri][7]);
  }
}

// ---------------- reduce gate partials + LSTM cell update (writes c, xh h-part)
__global__ __launch_bounds__(512) void k_lstm(
    const float* __restrict__ gp, const float* __restrict__ b_ih,
    const float* __restrict__ b_hh, float* __restrict__ cst, float* __restrict__ xh) {
  const int b = blockIdx.x, j = threadIdx.x;
  float g[4];
#pragma unroll
  for (int q = 0; q < 4; ++q) {
    float s = b_ih[q*HIDD + j] + b_hh[q*HIDD + j];
#pragma unroll
    for (int ks = 0; ks < KSG; ++ks) s += gp[((size_t)ks*BSZ + b)*G4D + q*HIDD + j];
    g[q] = s;
  }
  const float c_old = cst[(size_t)b*HIDD + j];
  const float ig = 1.0f / (1.0f + expf(-g[0]));
  const float fg = 1.0f / (1.0f + expf(-g[1]));
  const float gg = tanhf(g[2]);
  const float og = 1.0f / (1.0f + expf(-g[3]));
  const float cn = fg * c_old + ig * gg;
  const float hn = og * tanhf(cn);
  cst[(size_t)b*HIDD + j] = cn;
  xh[(size_t)b*KXD + IND + j] = hn;
}

// ---------------- scores partial: psc[b][mh][n] = sum_{m in mh-range} tanh(cp+hp)*w2
__global__ __launch_bounds__(256) void k_scores(
    const float* __restrict__ cp, const float* __restrict__ hpp,
    const float* __restrict__ w2, const int* __restrict__ clen,
    float* __restrict__ psc) {
  const int mh = blockIdx.x;  // [0,MSPLIT)
  const int b = blockIdx.y;
  const int tid = threadIdx.x;
  __shared__ float hs[128], ws[128];
  if (tid < 128) {
    const int m = mh * 128 + tid;
    float s = 0.0f;
#pragma unroll
    for (int ks = 0; ks < KSH; ++ks) s += hpp[((size_t)ks*BSZ + b)*MLPD + m];
    hs[tid] = s;
    ws[tid] = w2[m];
  }
  __syncthreads();
  const int len = clen[b];
  const int n0 = tid * 4;
  if (n0 >= len) return;
  float ax = 0, ay = 0, az = 0, aw = 0;
  const float* base = cp + ((size_t)b * MLPD + mh * 128) * NSQ + n0;
#pragma unroll 4
  for (int mm = 0; mm < 128; ++mm) {
    const float4 c4 = *(const float4*)(base + (size_t)mm * NSQ);
    const float h = hs[mm], w = ws[mm];
    ax = fmaf(tanh_fast(c4.x + h), w, ax);
    ay = fmaf(tanh_fast(c4.y + h), w, ay);
    az = fmaf(tanh_fast(c4.z + h), w, az);
    aw = fmaf(tanh_fast(c4.w + h), w, aw);
  }
  *(float4*)(psc + ((size_t)b * MSPLIT + mh) * NSQ + n0) = make_float4(ax, ay, az, aw);
}

// ---------------- argmax + LSE + lp + mask/x update (one block per batch row)
__global__ __launch_bounds__(256) void k_argmax(
    const float* __restrict__ psc, float* __restrict__ mask,
    const float* __restrict__ gum, const float* __restrict__ b2p,
    float* __restrict__ lp, const float* __restrict__ ctx,
    float* __restrict__ xh, float* __restrict__ outv, int step) {
  const int b = blockIdx.x, tid = threadIdx.x;
  __shared__ float rv[256], rs[256], rm[256];
  __shared__ int ri[256];
  __shared__ int sel;
  const float b2 = b2p[0];
  const int n0 = tid * 4;
  const float4 m4 = *(const float4*)(mask + (size_t)b * NSQ + n0);
  float sc[4] = {b2 + m4.x, b2 + m4.y, b2 + m4.z, b2 + m4.w};
#pragma unroll
  for (int mh = 0; mh < MSPLIT; ++mh) {
    const float4 p4 = *(const float4*)(psc + ((size_t)b * MSPLIT + mh) * NSQ + n0);
    sc[0] += p4.x; sc[1] += p4.y; sc[2] += p4.z; sc[3] += p4.w;
  }
  const float4 g4 = *(const float4*)(gum + ((size_t)step * BSZ + b) * NSQ + n0);
  const float gv[4] = {g4.x, g4.y, g4.z, g4.w};
  float bestv = -1e30f, bests = 0.0f, msc = -1e30f;
  int bestn = 0;
#pragma unroll
  for (int q = 0; q < 4; ++q) {
    const float v = sc[q] + gv[q];
    if (v > bestv) { bestv = v; bestn = n0 + q; bests = sc[q]; }
    msc = fmaxf(msc, sc[q]);
  }
  rv[tid] = bestv; ri[tid] = bestn; rs[tid] = bests; rm[tid] = msc;
  __syncthreads();
  for (int o = 128; o > 0; o >>= 1) {
    if (tid < o) {
      if (rv[tid+o] > rv[tid] || (rv[tid+o] == rv[tid] && ri[tid+o] < ri[tid])) {
        rv[tid] = rv[tid+o]; ri[tid] = ri[tid+o]; rs[tid] = rs[tid+o];
      }
      rm[tid] = fmaxf(rm[tid], rm[tid+o]);
    }
    __syncthreads();
  }
  const float M = rm[0];
  __syncthreads();
  float se = 0.0f;
#pragma unroll
  for (int q = 0; q < 4; ++q)
    se += __builtin_amdgcn_exp2f((sc[q] - M) * 1.4426950408889634f);
  rm[tid] = se;
  __syncthreads();
  for (int o = 128; o > 0; o >>= 1) {
    if (tid < o) rm[tid] += rm[tid+o];
    __syncthreads();
  }
  if (tid == 0) {
    const int n = ri[0];
    const float lse = M + logf(rm[0]);
    const float nlp = lp[b] + rs[0] - lse;
    lp[b] = nlp;
    mask[(size_t)b * NSQ + n] = NEGV;
    outv[step * BSZ + b] = (float)n;
    if (step == NSTEPC - 1) outv[NSTEPC * BSZ + b] = nlp;
    sel = n;
  }
  __syncthreads();
  const int n = sel;
  const float4* src = (const float4*)(ctx + ((size_t)b * NSQ + n) * IND);
  float4* dst = (float4*)(xh + (size_t)b * KXD);
  for (int d = tid; d < IND / 4; d += 256) dst[d] = src[d];
}

extern "C" void kernel_launch(void* const* d_in, const int* in_sizes, int n_in,
                              void* d_out, int out_size, void* d_ws, size_t ws_size,
                              hipStream_t stream) {
  const float* target_emb = (const float*)d_in[0];
  const float* ctx_emb   = (const float*)d_in[1];
  const int*   ctx_len   = (const int*)d_in[3];
  const float* W_ih = (const float*)d_in[5];
  const float* W_hh = (const float*)d_in[6];
  const float* b_ih = (const float*)d_in[7];
  const float* b_hh = (const float*)d_in[8];
  const float* W1c  = (const float*)d_in[9];
  const float* W1h  = (const float*)d_in[10];
  const float* b1   = (const float*)d_in[11];
  const float* w2   = (const float*)d_in[12];
  const float* b2   = (const float*)d_in[13];
  const float* gumbel = (const float*)d_in[14];
  float* out = (float*)d_out;

  float* ws = (float*)d_ws;
  size_t off = 0;
  auto alloc = [&](size_t n) { float* p = ws + off; off += (n + 63) & ~(size_t)63; return p; };

  float* cp   = alloc((size_t)BSZ * MLPD * NSQ);   // 268 MB
  float* gp   = alloc((size_t)KSG * BSZ * G4D);
  float* hpp  = alloc((size_t)KSH * BSZ * MLPD);
  float* psc  = alloc((size_t)BSZ * MSPLIT * NSQ);
  float* mask = alloc((size_t)BSZ * NSQ);
  float* xh   = alloc((size_t)BSZ * KXD);
  float* cst  = alloc((size_t)BSZ * HIDD);
  float* lp   = alloc(128);
  unsigned short* wfh = (unsigned short*)alloc(196608);   // 512x768 u16, frag-order
  unsigned short* wfl = (unsigned short*)alloc(196608);

  k_prep_wfrag<<<192, 256, 0, stream>>>(W1c, wfh, wfl);
  k_init<<<BSZ, 256, 0, stream>>>(target_emb, ctx_len, mask, xh, cst, lp);
  k_ctx9<<<1024, 512, 0, stream>>>(ctx_emb, wfh, wfl, b1, ctx_len, cp);

  for (int t = 0; t < NSTEPC; ++t) {
    // gates partials: N=2048, K=1280 split in 16 chunks of 5 tiles
    k_pgemm<<<dim3(G4D/128, KSG), 256, 0, stream>>>(
        xh, KXD, 0, W_ih, IND, IND, W_hh, HIDD, 5, G4D, gp);
    k_lstm<<<BSZ, 512, 0, stream>>>(gp, b_ih, b_hh, cst, xh);
    // hproj partials: N=512, K=512 split in 8 chunks of 4 tiles
    k_pgemm<<<dim3(MLPD/128, KSH), 256, 0, stream>>>(
        xh, KXD, IND, W1h, HIDD, 1 << 30, nullptr, 0, 4, MLPD, hpp);
    k_scores<<<dim3(MSPLIT, BSZ), 256, 0, stream>>>(cp, hpp, w2, ctx_len, psc);
    k_argmax<<<BSZ, 256, 0, stream>>>(psc, mask, gumbel, b2, lp, ctx_emb, xh, out, t);
  }
}

// Round 12
// 796.698 us; speedup vs baseline: 1.2611x; 1.0757x over previous
//
#include <hip/hip_runtime.h>
#include <hip/hip_bf16.h>

#define BSZ 128
#define NSQ 1024
#define NSTEPC 8
#define IND 768
#define HIDD 512
#define G4D 2048
#define MLPD 512
#define KXD 1280
#define NEGV -100000.0f
#define KSG 16   // K-split chunks for gates gemm (1280/16 = 80 = 5 tiles)
#define KSH 8    // K-split chunks for hproj gemm (512/8 = 64 = 4 tiles)
#define MSPLIT 4 // m-split for scores kernel

typedef __attribute__((ext_vector_type(4))) float f32x4;
typedef __attribute__((ext_vector_type(8))) short short8v;

__device__ __forceinline__ void split2(float4 f0, float4 f1, short8v& hi, short8v& lo) {
  float fv[8] = {f0.x, f0.y, f0.z, f0.w, f1.x, f1.y, f1.z, f1.w};
#pragma unroll
  for (int j = 0; j < 8; ++j) {
    const unsigned ub = __builtin_bit_cast(unsigned, fv[j]);
    const unsigned hb = ub & 0xFFFF0000u;
    const float lf = fv[j] - __builtin_bit_cast(float, hb);
    hi[j] = (short)(hb >> 16);
    lo[j] = (short)(__builtin_bit_cast(unsigned, lf) >> 16);
  }
}

// tanh(x) = 1 - 2/(e^{2x}+1)
__device__ __forceinline__ float tanh_fast(float x) {
  x = fminf(fmaxf(x, -15.0f), 15.0f);
  float e = __builtin_amdgcn_exp2f(x * 2.8853900817779268f);
  float r = __builtin_amdgcn_rcpf(e + 1.0f);
  return fmaf(-2.0f, r, 1.0f);
}

// ---------------- one-time: split W1c into FRAGMENT-ORDER bf16 hi/lo planes.
// wave w = row>>6 (8 m-groups of 64), frag f=(row>>4)&3, l15=row&15,
// tile t=k>>5, l4=(k>>3)&3. unit16B = ((w*24 + t)*4 + f)*64 + l4*16 + l15
__global__ __launch_bounds__(256) void k_prep_wfrag(
    const float* __restrict__ W1c,
    unsigned short* __restrict__ wfh, unsigned short* __restrict__ wfl) {
  const int c = blockIdx.x * 256 + threadIdx.x;
  if (c >= 49152) return;  // 512 rows x 96 chunks of 8 k-elements
  const int row = c / 96, wc = c - row * 96;
  const int w = row >> 6;
  const int f = (row >> 4) & 3, l15 = row & 15;
  const int t = wc >> 2, l4 = wc & 3;
  const size_t unit = (((size_t)(w * 24 + t) * 4 + f) * 64) + l4 * 16 + l15;
  const float* src = W1c + (size_t)row * IND + wc * 8;
  const float4 f0 = *(const float4*)src, f1 = *(const float4*)(src + 4);
  short8v hi, lo;
  split2(f0, f1, hi, lo);
  *(short8v*)(wfh + unit * 8) = hi;
  *(short8v*)(wfl + unit * 8) = lo;
}

// ---------------- init: mask from ctx_len, xh = [target_emb | 0], c=0, lp=0
__global__ __launch_bounds__(256) void k_init(
    const float* __restrict__ te, const int* __restrict__ cl,
    float* __restrict__ mask, float* __restrict__ xh,
    float* __restrict__ cst, float* __restrict__ lp) {
  const int b = blockIdx.x, tid = threadIdx.x;
  const int L = cl[b];
  for (int n = tid; n < NSQ; n += 256) mask[(size_t)b*NSQ + n] = (n >= L) ? NEGV : 0.0f;
  for (int d = tid; d < IND; d += 256) xh[(size_t)b*KXD + d] = te[(size_t)b*IND + d];
  for (int j = tid; j < HIDD; j += 256) {
    xh[(size_t)b*KXD + IND + j] = 0.0f;
    cst[(size_t)b*HIDD + j] = 0.0f;
  }
  if (tid == 0) lp[b] = 0.0f;
}

// ---------------- ctx GEMM, BM=512 x BN=128, 1024 thr / 16 waves:
// same minimal bytes as ctx9 (ctx once/strip, W L2-hot) but 4 waves/SIMD
// for latency hiding. Wave (wm 0..7, wn 0..1) owns m-64 x n-64, acc 4x4.
// ctx split once into XOR-swizzled LDS planes (dbuf), staging spread over
// all 1024 threads (4 floats each, linear 8B ds_write = 2-way free).
__global__ __launch_bounds__(1024, 1) void k_ctx10(
    const float* __restrict__ ctx,
    const unsigned short* __restrict__ wfh, const unsigned short* __restrict__ wfl,
    const float* __restrict__ bias, const int* __restrict__ clen,
    float* __restrict__ cp) {
  __shared__ __align__(16) unsigned short sCh[2][4096], sCl[2][4096];  // 128r x 32k
  const int strip = blockIdx.x;          // 1024 n-strips
  const int b = strip >> 3;
  const int nbase = (strip & 7) << 7;
  if (nbase >= clen[b]) return;          // masked region: cp never read there
  const int i0 = strip << 7;
  const int tid = threadIdx.x;
  const int lane = tid & 63, wid = tid >> 6;
  const int wm = wid >> 1, wn = wid & 1;
  const int l15 = lane & 15, l4 = lane >> 4;
  // staging decomposition: thread -> 4 k-elements of one row
  const int srow = tid >> 3, sks = tid & 7;
  const int sslot = sks >> 1, shalf = sks & 1;
  const int sswz = (srow >> 1) & 3;
  const float* ssrc = ctx + (size_t)(i0 + srow) * IND + ((sslot ^ sswz) * 8 + shalf * 4);
  const int soff = srow * 32 + sslot * 8 + shalf * 4;   // shorts
  // W frag base (shorts): ((wm*24 + t)*4 + f)*512 + lane*8
  const size_t wbase = (size_t)(wm * 24) * 2048 + lane * 8;

  auto stage = [&](int t, int buf) {
    const float4 q = *(const float4*)(ssrc + t * 32);
    unsigned h01, h23, l01, l23;
    {
      const float qq[4] = {q.x, q.y, q.z, q.w};
      unsigned hh[4], ll[4];
#pragma unroll
      for (int j = 0; j < 4; ++j) {
        const unsigned ub = __builtin_bit_cast(unsigned, qq[j]);
        const unsigned hb = ub & 0xFFFF0000u;
        const float lf = qq[j] - __builtin_bit_cast(float, hb);
        hh[j] = hb >> 16;
        ll[j] = __builtin_bit_cast(unsigned, lf) >> 16;
      }
      h01 = hh[0] | (hh[1] << 16); h23 = hh[2] | (hh[3] << 16);
      l01 = ll[0] | (ll[1] << 16); l23 = ll[2] | (ll[3] << 16);
    }
    *(uint2*)&sCh[buf][soff] = make_uint2(h01, h23);
    *(uint2*)&sCl[buf][soff] = make_uint2(l01, l23);
  };

  stage(0, 0);   // prologue

  f32x4 acc[4][4] = {};  // [fm][fn]
  for (int t = 0; t < 24; ++t) {
    __syncthreads();                       // buf[t&1] ready
    const int cur = t & 1;
    // W frags for this tile: direct coalesced loads (L2-hot frag-order)
    short8v wh[4], wl[4];
    const size_t toff = wbase + (size_t)t * 2048;
#pragma unroll
    for (int f = 0; f < 4; ++f) {
      wh[f] = *(const short8v*)(wfh + toff + f * 512);
      wl[f] = *(const short8v*)(wfl + toff + f * 512);
    }
#pragma unroll
    for (int fn = 0; fn < 4; ++fn) {
      const int rc = wn * 64 + fn * 16 + l15;
      const int so = (l4 ^ ((rc >> 1) & 3)) << 3;
      const short8v bhv = *(const short8v*)&sCh[cur][rc * 32 + so];
      const short8v blv = *(const short8v*)&sCl[cur][rc * 32 + so];
      __builtin_amdgcn_s_setprio(1);
#pragma unroll
      for (int fm = 0; fm < 4; ++fm) {
        acc[fm][fn] = __builtin_amdgcn_mfma_f32_16x16x32_bf16(wh[fm], bhv, acc[fm][fn], 0, 0, 0);
        acc[fm][fn] = __builtin_amdgcn_mfma_f32_16x16x32_bf16(wh[fm], blv, acc[fm][fn], 0, 0, 0);
        acc[fm][fn] = __builtin_amdgcn_mfma_f32_16x16x32_bf16(wl[fm], bhv, acc[fm][fn], 0, 0, 0);
      }
      __builtin_amdgcn_s_setprio(0);
    }
    if (t + 1 < 24) stage(t + 1, cur ^ 1);   // disjoint buffer, pre-barrier safe
  }
  // epilogue: m = wm*64 + fm*16 + l4*4 + r, n = nbase + wn*64 + fn*16 + l15
#pragma unroll
  for (int fm = 0; fm < 4; ++fm) {
#pragma unroll
    for (int r = 0; r < 4; ++r) {
      const int m = wm * 64 + fm * 16 + l4 * 4 + r;
      const float bb = bias[m];
      float* dst = cp + (((size_t)(b * MLPD + m)) << 10) + nbase + wn * 64 + l15;
#pragma unroll
      for (int fn = 0; fn < 4; ++fn)
        dst[fn * 16] = acc[fm][fn][r] + bb;
    }
  }
}

// ---------------- K-split partial GEMM: P[kc][i][n] = sum_{k in chunk} A[i,k]*B(n,k)
__global__ __launch_bounds__(256) void k_pgemm(
    const float* __restrict__ A, int lda, int acol,
    const float* __restrict__ B0, int ldb0, int kb,
    const float* __restrict__ B1, int ldb1,
    int kTiles, int N, float* __restrict__ P) {
  __shared__ float As[16][128];
  __shared__ float Bs[16][132];
  const int n0 = blockIdx.x * 128;
  const int kc0 = blockIdx.y * kTiles * 16;
  const int tid = threadIdx.x;
  const int tn = tid & 15;   // n-group
  const int ta = tid >> 4;   // i-group
  float acc[8][8] = {};      // [ri][ni]
  for (int t = 0; t < kTiles; ++t) {
    const int k0 = kc0 + t * 16;
#pragma unroll
    for (int u = 0; u < 2; ++u) {
      const int v = tid + u * 256;
      const int r = v >> 2, kc = v & 3;
      const float4 a4 = *(const float4*)(A + (size_t)r * lda + acol + k0 + kc * 4);
      As[kc*4+0][r] = a4.x; As[kc*4+1][r] = a4.y; As[kc*4+2][r] = a4.z; As[kc*4+3][r] = a4.w;
      const float* bp = (k0 < kb) ? (B0 + (size_t)(n0 + r) * ldb0 + k0 + kc * 4)
                                  : (B1 + (size_t)(n0 + r) * ldb1 + (k0 - kb) + kc * 4);
      const float4 b4 = *(const float4*)bp;
      Bs[kc*4+0][r] = b4.x; Bs[kc*4+1][r] = b4.y; Bs[kc*4+2][r] = b4.z; Bs[kc*4+3][r] = b4.w;
    }
    __syncthreads();
#pragma unroll
    for (int kk = 0; kk < 16; ++kk) {
      float av[8], bv[8];
#pragma unroll
      for (int q = 0; q < 8; ++q) av[q] = As[kk][ta*8+q];
#pragma unroll
      for (int q = 0; q < 8; ++q) bv[q] = Bs[kk][tn*8+q];
#pragma unroll
      for (int ri = 0; ri < 8; ++ri)
#pragma unroll
        for (int ni = 0; ni < 8; ++ni)
          acc[ri][ni] = fmaf(av[ri], bv[ni], acc[ri][ni]);
    }
    __syncthreads();
  }
#pragma unroll
  for (int ri = 0; ri < 8; ++ri) {
    const int i = ta * 8 + ri;
    float* p = P + ((size_t)blockIdx.y * BSZ + i) * N + n0 + tn * 8;
    *(float4*)(p + 0) = make_float4(acc[ri][0], acc[ri][1], acc[ri][2], acc[ri][3]);
    *(float4*)(p + 4) = make_float4(acc[ri][4], acc[ri][5], acc[ri][6], acc[ri][7]);
  }
}

// ---------------- reduce gate partials + LSTM cell update (writes c, xh h-part)
__global__ __launch_bounds__(512) void k_lstm(
    const float* __restrict__ gp, const float* __restrict__ b_ih,
    const float* __restrict__ b_hh, float* __restrict__ cst, float* __restrict__ xh) {
  const int b = blockIdx.x, j = threadIdx.x;
  float g[4];
#pragma unroll
  for (int q = 0; q < 4; ++q) {
    float s = b_ih[q*HIDD + j] + b_hh[q*HIDD + j];
#pragma unroll
    for (int ks = 0; ks < KSG; ++ks) s += gp[((size_t)ks*BSZ + b)*G4D + q*HIDD + j];
    g[q] = s;
  }
  const float c_old = cst[(size_t)b*HIDD + j];
  const float ig = 1.0f / (1.0f + expf(-g[0]));
  const float fg = 1.0f / (1.0f + expf(-g[1]));
  const float gg = tanhf(g[2]);
  const float og = 1.0f / (1.0f + expf(-g[3]));
  const float cn = fg * c_old + ig * gg;
  const float hn = og * tanhf(cn);
  cst[(size_t)b*HIDD + j] = cn;
  xh[(size_t)b*KXD + IND + j] = hn;
}

// ---------------- scores partial: psc[b][mh][n] = sum_{m in mh-range} tanh(cp+hp)*w2
__global__ __launch_bounds__(256) void k_scores(
    const float* __restrict__ cp, const float* __restrict__ hpp,
    const float* __restrict__ w2, const int* __restrict__ clen,
    float* __restrict__ psc) {
  const int mh = blockIdx.x;  // [0,MSPLIT)
  const int b = blockIdx.y;
  const int tid = threadIdx.x;
  __shared__ float hs[128], ws[128];
  if (tid < 128) {
    const int m = mh * 128 + tid;
    float s = 0.0f;
#pragma unroll
    for (int ks = 0; ks < KSH; ++ks) s += hpp[((size_t)ks*BSZ + b)*MLPD + m];
    hs[tid] = s;
    ws[tid] = w2[m];
  }
  __syncthreads();
  const int len = clen[b];
  const int n0 = tid * 4;
  if (n0 >= len) return;
  float ax = 0, ay = 0, az = 0, aw = 0;
  const float* base = cp + ((size_t)b * MLPD + mh * 128) * NSQ + n0;
#pragma unroll 4
  for (int mm = 0; mm < 128; ++mm) {
    const float4 c4 = *(const float4*)(base + (size_t)mm * NSQ);
    const float h = hs[mm], w = ws[mm];
    ax = fmaf(tanh_fast(c4.x + h), w, ax);
    ay = fmaf(tanh_fast(c4.y + h), w, ay);
    az = fmaf(tanh_fast(c4.z + h), w, az);
    aw = fmaf(tanh_fast(c4.w + h), w, aw);
  }
  *(float4*)(psc + ((size_t)b * MSPLIT + mh) * NSQ + n0) = make_float4(ax, ay, az, aw);
}

// ---------------- argmax + LSE + lp + mask/x update (one block per batch row)
__global__ __launch_bounds__(256) void k_argmax(
    const float* __restrict__ psc, float* __restrict__ mask,
    const float* __restrict__ gum, const float* __restrict__ b2p,
    float* __restrict__ lp, const float* __restrict__ ctx,
    float* __restrict__ xh, float* __restrict__ outv, int step) {
  const int b = blockIdx.x, tid = threadIdx.x;
  __shared__ float rv[256], rs[256], rm[256];
  __shared__ int ri[256];
  __shared__ int sel;
  const float b2 = b2p[0];
  const int n0 = tid * 4;
  const float4 m4 = *(const float4*)(mask + (size_t)b * NSQ + n0);
  float sc[4] = {b2 + m4.x, b2 + m4.y, b2 + m4.z, b2 + m4.w};
#pragma unroll
  for (int mh = 0; mh < MSPLIT; ++mh) {
    const float4 p4 = *(const float4*)(psc + ((size_t)b * MSPLIT + mh) * NSQ + n0);
    sc[0] += p4.x; sc[1] += p4.y; sc[2] += p4.z; sc[3] += p4.w;
  }
  const float4 g4 = *(const float4*)(gum + ((size_t)step * BSZ + b) * NSQ + n0);
  const float gv[4] = {g4.x, g4.y, g4.z, g4.w};
  float bestv = -1e30f, bests = 0.0f, msc = -1e30f;
  int bestn = 0;
#pragma unroll
  for (int q = 0; q < 4; ++q) {
    const float v = sc[q] + gv[q];
    if (v > bestv) { bestv = v; bestn = n0 + q; bests = sc[q]; }
    msc = fmaxf(msc, sc[q]);
  }
  rv[tid] = bestv; ri[tid] = bestn; rs[tid] = bests; rm[tid] = msc;
  __syncthreads();
  for (int o = 128; o > 0; o >>= 1) {
    if (tid < o) {
      if (rv[tid+o] > rv[tid] || (rv[tid+o] == rv[tid] && ri[tid+o] < ri[tid])) {
        rv[tid] = rv[tid+o]; ri[tid] = ri[tid+o]; rs[tid] = rs[tid+o];
      }
      rm[tid] = fmaxf(rm[tid], rm[tid+o]);
    }
    __syncthreads();
  }
  const float M = rm[0];
  __syncthreads();
  float se = 0.0f;
#pragma unroll
  for (int q = 0; q < 4; ++q)
    se += __builtin_amdgcn_exp2f((sc[q] - M) * 1.4426950408889634f);
  rm[tid] = se;
  __syncthreads();
  for (int o = 128; o > 0; o >>= 1) {
    if (tid < o) rm[tid] += rm[tid+o];
    __syncthreads();
  }
  if (tid == 0) {
    const int n = ri[0];
    const float lse = M + logf(rm[0]);
    const float nlp = lp[b] + rs[0] - lse;
    lp[b] = nlp;
    mask[(size_t)b * NSQ + n] = NEGV;
    outv[step * BSZ + b] = (float)n;
    if (step == NSTEPC - 1) outv[NSTEPC * BSZ + b] = nlp;
    sel = n;
  }
  __syncthreads();
  const int n = sel;
  const float4* src = (const float4*)(ctx + ((size_t)b * NSQ + n) * IND);
  float4* dst = (float4*)(xh + (size_t)b * KXD);
  for (int d = tid; d < IND / 4; d += 256) dst[d] = src[d];
}

extern "C" void kernel_launch(void* const* d_in, const int* in_sizes, int n_in,
                              void* d_out, int out_size, void* d_ws, size_t ws_size,
                              hipStream_t stream) {
  const float* target_emb = (const float*)d_in[0];
  const float* ctx_emb   = (const float*)d_in[1];
  const int*   ctx_len   = (const int*)d_in[3];
  const float* W_ih = (const float*)d_in[5];
  const float* W_hh = (const float*)d_in[6];
  const float* b_ih = (const float*)d_in[7];
  const float* b_hh = (const float*)d_in[8];
  const float* W1c  = (const float*)d_in[9];
  const float* W1h  = (const float*)d_in[10];
  const float* b1   = (const float*)d_in[11];
  const float* w2   = (const float*)d_in[12];
  const float* b2   = (const float*)d_in[13];
  const float* gumbel = (const float*)d_in[14];
  float* out = (float*)d_out;

  float* ws = (float*)d_ws;
  size_t off = 0;
  auto alloc = [&](size_t n) { float* p = ws + off; off += (n + 63) & ~(size_t)63; return p; };

  float* cp   = alloc((size_t)BSZ * MLPD * NSQ);   // 268 MB
  float* gp   = alloc((size_t)KSG * BSZ * G4D);
  float* hpp  = alloc((size_t)KSH * BSZ * MLPD);
  float* psc  = alloc((size_t)BSZ * MSPLIT * NSQ);
  float* mask = alloc((size_t)BSZ * NSQ);
  float* xh   = alloc((size_t)BSZ * KXD);
  float* cst  = alloc((size_t)BSZ * HIDD);
  float* lp   = alloc(128);
  unsigned short* wfh = (unsigned short*)alloc(196608);   // 512x768 u16, frag-order
  unsigned short* wfl = (unsigned short*)alloc(196608);

  k_prep_wfrag<<<192, 256, 0, stream>>>(W1c, wfh, wfl);
  k_init<<<BSZ, 256, 0, stream>>>(target_emb, ctx_len, mask, xh, cst, lp);
  k_ctx10<<<1024, 1024, 0, stream>>>(ctx_emb, wfh, wfl, b1, ctx_len, cp);

  for (int t = 0; t < NSTEPC; ++t) {
    // gates partials: N=2048, K=1280 split in 16 chunks of 5 tiles
    k_pgemm<<<dim3(G4D/128, KSG), 256, 0, stream>>>(
        xh, KXD, 0, W_ih, IND, IND, W_hh, HIDD, 5, G4D, gp);
    k_lstm<<<BSZ, 512, 0, stream>>>(gp, b_ih, b_hh, cst, xh);
    // hproj partials: N=512, K=512 split in 8 chunks of 4 tiles
    k_pgemm<<<dim3(MLPD/128, KSH), 256, 0, stream>>>(
        xh, KXD, IND, W1h, HIDD, 1 << 30, nullptr, 0, 4, MLPD, hpp);
    k_scores<<<dim3(MSPLIT, BSZ), 256, 0, stream>>>(cp, hpp, w2, ctx_len, psc);
    k_argmax<<<BSZ, 256, 0, stream>>>(psc, mask, gumbel, b2, lp, ctx_emb, xh, out, t);
  }
}